// Round 3
// baseline (663.806 us; speedup 1.0000x reference)
//
#include <hip/hip_runtime.h>
#include <hip/hip_fp16.h>

typedef __attribute__((ext_vector_type(8))) _Float16 f16x8;
typedef __attribute__((ext_vector_type(4))) _Float16 f16x4;
typedef __attribute__((ext_vector_type(2))) _Float16 f16x2;
typedef __attribute__((ext_vector_type(4))) float f32x4;

#define RES 512
#define ED 256
#define HID 128
#define NTILES 16384          // 1M points / 64 per tile
#define GRID 512

// d_ws layout (units: halfs)
#define WS_EMB0 0
#define WS_EMB1 131072
#define WS_W0   262144
#define WS_W1   294912
#define WS_W2   311296

__global__ void prep_kernel(const float* __restrict__ emb0, const float* __restrict__ emb1,
                            const float* __restrict__ w0, const float* __restrict__ w1,
                            const float* __restrict__ w2, f16x2* __restrict__ dst) {
  int idx = blockIdx.x * 256 + threadIdx.x;       // f32-pair index == f16-pair index
  const float* src; int rel;
  if      (idx <  65536) { src = emb0; rel = idx; }
  else if (idx < 131072) { src = emb1; rel = idx - 65536; }
  else if (idx < 147456) { src = w0;   rel = idx - 131072; }
  else if (idx < 155648) { src = w1;   rel = idx - 147456; }
  else if (idx < 155840) { src = w2;   rel = idx - 155648; }
  else return;
  float2 v = ((const float2*)src)[rel];
  f16x2 h; h[0] = (_Float16)v.x; h[1] = (_Float16)v.y;
  dst[idx] = h;
}

__global__ __launch_bounds__(512, 4) void axisnet_kernel(
    const float* __restrict__ coords,
    const float* __restrict__ b0, const float* __restrict__ b1,
    const float* __restrict__ b2,
    const _Float16* __restrict__ ws, float* __restrict__ out)
{
  __shared__ _Float16 e_smem[64 * 256];   // 32 KiB, rows of 512 B, XOR-swizzled
  __shared__ _Float16 h_smem[64 * 128];   // 16 KiB, rows of 256 B, XOR-swizzled
  char* eb = (char*)e_smem;
  char* hb = (char*)h_smem;

  const _Float16* emb0h = ws + WS_EMB0;
  const _Float16* emb1h = ws + WS_EMB1;
  const _Float16* w0h   = ws + WS_W0;
  const _Float16* w1h   = ws + WS_W1;
  const _Float16* w2h   = ws + WS_W2;

  const int tid  = threadIdx.x;
  const int lane = tid & 63;
  const int wv   = tid >> 6;        // 0..7
  const int g    = lane >> 4;       // k-group 0..3
  const int lr   = lane & 15;
  const int wm   = wv >> 2;         // layer0: row half (32 rows)
  const int wc   = wv & 3;          // layer0: col block (32 cols)

  // ---- persistent B fragments (fp16, loaded once per block; zero VALU) ----
  // layer0: cols 32*wc + 16*nt + lr, k = 32*ks + 8*g + j
  f16x8 w0f[2][8];
#pragma unroll
  for (int nt = 0; nt < 2; ++nt) {
    const _Float16* p = w0h + (size_t)(32*wc + 16*nt + lr)*ED + 8*g;
#pragma unroll
    for (int ks = 0; ks < 8; ++ks) w0f[nt][ks] = *(const f16x8*)(p + 32*ks);
  }
  float b0v[2];
  b0v[0] = b0[32*wc + lr];
  b0v[1] = b0[32*wc + 16 + lr];

  // layer1: cols 16*wv + lr (16 cols/wave)
  f16x8 w1f[4];
  {
    const _Float16* p = w1h + (size_t)(16*wv + lr)*HID + 8*g;
#pragma unroll
    for (int ks = 0; ks < 4; ++ks) w1f[ks] = *(const f16x8*)(p + 32*ks);
  }
  const float b1v = b1[16*wv + lr];

  // layer2: waves 0-3, real cols lr<3, rest zero-padded
  f16x8 w2f[4] = {};
  if (wv < 4 && lr < 3) {
    const _Float16* p = w2h + (size_t)lr*HID + 8*g;
#pragma unroll
    for (int ks = 0; ks < 4; ++ks) w2f[ks] = *(const f16x8*)(p + 32*ks);
  }
  const float b2v = (lr < 3) ? b2[lr] : 0.f;

  const int pp = lane & 7;          // point slot this lane precomputes

  for (int tile = blockIdx.x; tile < NTILES; tile += GRID) {
    const int base = tile * 64;

    // ---- gather + bilinear lerp (packed fp16 math) ----
    // per-lane setup for owned point, broadcast via shfl
    float2 cp = ((const float2*)coords)[base + 8*wv + pp];
    float c0 = fminf(fmaxf(cp.x, -1.f), 0.999f);
    float c1 = fminf(fmaxf(cp.y, -1.f), 0.999f);
    float a0 = (0.5f*c0 + 0.5f) * 511.f;
    float a1 = (0.5f*c1 + 0.5f) * 511.f;
    int i0 = (int)a0, i1 = (int)a1;
    float wa = a0 - (float)i0, wb = a1 - (float)i1;
    int o0 = i0 << 9, o1 = i1 << 9;      // byte row offsets (512 B/row)

#pragma unroll
    for (int i = 0; i < 8; ++i) {
      int   oo0 = __shfl(o0, i);
      int   oo1 = __shfl(o1, i);
      float waf = __shfl(wa, i);
      float wbf = __shfl(wb, i);
      _Float16 wah = (_Float16)waf, wbh = (_Float16)wbf;
      f16x4 wa4 = {wah, wah, wah, wah};
      f16x4 wb4 = {wbh, wbh, wbh, wbh};
      const char* px = (const char*)emb0h + oo0 + 8*lane;   // lane covers elems 4l..4l+3
      const char* py = (const char*)emb1h + oo1 + 8*lane;
      f16x4 x0 = *(const f16x4*)px;
      f16x4 x1 = *(const f16x4*)(px + 512);
      f16x4 y0 = *(const f16x4*)py;
      f16x4 y1 = *(const f16x4*)(py + 512);
      f16x4 ev = (x0 + wa4*(x1 - x0)) * (y0 + wb4*(y1 - y0));
      int row = 8*wv + i;
      *(f16x4*)(eb + row*512 + ((8*lane) ^ ((row & 7) << 4))) = ev;
    }
    __syncthreads();

    // ---- layer 0: [64x256] @ [256x128], wave = (wm,wc): 32 rows x 32 cols ----
    f32x4 acc[2][2];
#pragma unroll
    for (int mt = 0; mt < 2; ++mt) { acc[mt][0] = (f32x4)0.f; acc[mt][1] = (f32x4)0.f; }
#pragma unroll
    for (int ks = 0; ks < 8; ++ks) {
#pragma unroll
      for (int mt = 0; mt < 2; ++mt) {
        int row = 32*wm + 16*mt + lr;
        f16x8 a = *(const f16x8*)(eb + row*512 + ((64*ks + 16*g) ^ ((lr & 7) << 4)));
        acc[mt][0] = __builtin_amdgcn_mfma_f32_16x16x32_f16(a, w0f[0][ks], acc[mt][0], 0, 0, 0);
        acc[mt][1] = __builtin_amdgcn_mfma_f32_16x16x32_f16(a, w0f[1][ks], acc[mt][1], 0, 0, 0);
      }
    }
    // epilogue: sin(30(x+b)) -> h_smem   (C layout: row=4g+r, col=lr)
#pragma unroll
    for (int mt = 0; mt < 2; ++mt)
#pragma unroll
      for (int nt = 0; nt < 2; ++nt)
#pragma unroll
        for (int r = 0; r < 4; ++r) {
          float h = __sinf(30.f * (acc[mt][nt][r] + b0v[nt]));
          int row  = 32*wm + 16*mt + 4*g + r;
          int colb = 2*(32*wc + 16*nt + lr);
          *(_Float16*)(hb + row*256 + (colb ^ ((row & 7) << 4))) = (_Float16)h;
        }
    __syncthreads();

    // ---- layer 1: [64x128] @ [128x128], 16 cols/wave ----
    f32x4 acc1[4];
#pragma unroll
    for (int mt = 0; mt < 4; ++mt) acc1[mt] = (f32x4)0.f;
#pragma unroll
    for (int ks = 0; ks < 4; ++ks)
#pragma unroll
      for (int mt = 0; mt < 4; ++mt) {
        int row = 16*mt + lr;
        f16x8 a = *(const f16x8*)(hb + row*256 + ((64*ks + 16*g) ^ ((lr & 7) << 4)));
        acc1[mt] = __builtin_amdgcn_mfma_f32_16x16x32_f16(a, w1f[ks], acc1[mt], 0, 0, 0);
      }
    __syncthreads();   // all h0 reads done before h1 overwrites
#pragma unroll
    for (int mt = 0; mt < 4; ++mt)
#pragma unroll
      for (int r = 0; r < 4; ++r) {
        float h = __sinf(30.f * (acc1[mt][r] + b1v));
        int row  = 16*mt + 4*g + r;
        int colb = 2*(16*wv + lr);
        *(_Float16*)(hb + row*256 + (colb ^ ((row & 7) << 4))) = (_Float16)h;
      }
    __syncthreads();

    // ---- layer 2: [64x128] @ [128x3] (padded to 16 cols), waves 0-3 ----
    if (wv < 4) {
      f32x4 acc2 = (f32x4)0.f;
#pragma unroll
      for (int ks = 0; ks < 4; ++ks) {
        int row = 16*wv + lr;
        f16x8 a = *(const f16x8*)(hb + row*256 + ((64*ks + 16*g) ^ ((lr & 7) << 4)));
        acc2 = __builtin_amdgcn_mfma_f32_16x16x32_f16(a, w2f[ks], acc2, 0, 0, 0);
      }
      if (lr < 3) {
#pragma unroll
        for (int r = 0; r < 4; ++r) {
          int pt = base + 16*wv + 4*g + r;
          out[pt*3 + lr] = acc2[r] + b2v;
        }
      }
    }
    // next-tile gather writes e_smem only; every wave's reads of e/h this tile
    // precede the barriers the writer must cross first -> no extra barrier.
  }
}

extern "C" void kernel_launch(void* const* d_in, const int* in_sizes, int n_in,
                              void* d_out, int out_size, void* d_ws, size_t ws_size,
                              hipStream_t stream) {
  const float* coords = (const float*)d_in[0];
  const float* emb0   = (const float*)d_in[1];
  const float* emb1   = (const float*)d_in[2];
  const float* w0     = (const float*)d_in[3];
  const float* b0     = (const float*)d_in[4];
  const float* w1     = (const float*)d_in[5];
  const float* b1     = (const float*)d_in[6];
  const float* w2     = (const float*)d_in[7];
  const float* b2     = (const float*)d_in[8];
  float* out = (float*)d_out;
  _Float16* ws = (_Float16*)d_ws;

  // fp16 conversion of tables + weights into workspace (idempotent, every call)
  prep_kernel<<<(155840 + 255)/256, 256, 0, stream>>>(emb0, emb1, w0, w1, w2, (f16x2*)ws);

  axisnet_kernel<<<GRID, 512, 0, stream>>>(coords, b0, b1, b2,
                                           (const _Float16*)ws, out);
}

// Round 4
// 362.214 us; speedup vs baseline: 1.8326x; 1.8326x over previous
//
#include <hip/hip_runtime.h>
#include <hip/hip_fp16.h>

typedef __attribute__((ext_vector_type(8))) _Float16 f16x8;
typedef __attribute__((ext_vector_type(4))) _Float16 f16x4;
typedef __attribute__((ext_vector_type(2))) _Float16 f16x2;
typedef __attribute__((ext_vector_type(4))) float f32x4;

#define RES 512
#define ED 256
#define HID 128
#define NTILES 16384          // 1M points / 64 per tile
#define GRID 512

// d_ws layout (units: halfs)
#define WS_EMB0 0
#define WS_EMB1 131072
#define WS_W0   262144
#define WS_W1   294912
#define WS_W2   311296

__global__ void prep_kernel(const float* __restrict__ emb0, const float* __restrict__ emb1,
                            const float* __restrict__ w0, const float* __restrict__ w1,
                            const float* __restrict__ w2, f16x2* __restrict__ dst) {
  int idx = blockIdx.x * 256 + threadIdx.x;       // f32-pair index == f16-pair index
  const float* src; int rel;
  if      (idx <  65536) { src = emb0; rel = idx; }
  else if (idx < 131072) { src = emb1; rel = idx - 65536; }
  else if (idx < 147456) { src = w0;   rel = idx - 131072; }
  else if (idx < 155648) { src = w1;   rel = idx - 147456; }
  else if (idx < 155840) { src = w2;   rel = idx - 155648; }
  else return;
  float2 v = ((const float2*)src)[rel];
  f16x2 h; h[0] = (_Float16)v.x; h[1] = (_Float16)v.y;
  dst[idx] = h;
}

// launch_bounds 2nd arg behaves as min BLOCKS/CU (CUDA semantics): 2 blocks
// x 8 waves = 16 waves/CU -> 128-VGPR cap. Round 3's (512,4) forced a 64-reg
// cap and spilled ~1 GB/dispatch of w-fragments to scratch (FETCH 983 MB).
__global__ __launch_bounds__(512, 2) void axisnet_kernel(
    const float* __restrict__ coords,
    const float* __restrict__ b0, const float* __restrict__ b1,
    const float* __restrict__ b2,
    const _Float16* __restrict__ ws, float* __restrict__ out)
{
  __shared__ _Float16 e_smem[64 * 256];   // 32 KiB, rows of 512 B, XOR-swizzled
  __shared__ _Float16 h_smem[64 * 128];   // 16 KiB, rows of 256 B, XOR-swizzled
  char* eb = (char*)e_smem;
  char* hb = (char*)h_smem;

  const _Float16* emb0h = ws + WS_EMB0;
  const _Float16* emb1h = ws + WS_EMB1;
  const _Float16* w0h   = ws + WS_W0;
  const _Float16* w1h   = ws + WS_W1;
  const _Float16* w2h   = ws + WS_W2;

  const int tid  = threadIdx.x;
  const int lane = tid & 63;
  const int wv   = tid >> 6;        // 0..7
  const int g    = lane >> 4;       // k-group 0..3
  const int lr   = lane & 15;

  // ---- persistent B fragments (fp16, once per block): 32+16+16 = 64 VGPRs ----
  // Wave wv owns output cols 16*wv..16*wv+15 for BOTH layer 0 and layer 1.
  // B layout for mfma 16x16x32: lane gives B[k][col], col=lr, k=32*ks+8*g+j.
  const int ncol = 16*wv + lr;
  f16x8 w0f[8];
  {
    const _Float16* p = w0h + (size_t)ncol*ED + 8*g;
#pragma unroll
    for (int ks = 0; ks < 8; ++ks) w0f[ks] = *(const f16x8*)(p + 32*ks);
  }
  f16x8 w1f[4];
  {
    const _Float16* p = w1h + (size_t)ncol*HID + 8*g;
#pragma unroll
    for (int ks = 0; ks < 4; ++ks) w1f[ks] = *(const f16x8*)(p + 32*ks);
  }
  const float b0v = b0[ncol];
  const float b1v = b1[ncol];

  // layer2: waves 0-3, real cols lr<3, rest zero-padded
  f16x8 w2f[4] = {};
  if (wv < 4 && lr < 3) {
    const _Float16* p = w2h + (size_t)lr*HID + 8*g;
#pragma unroll
    for (int ks = 0; ks < 4; ++ks) w2f[ks] = *(const f16x8*)(p + 32*ks);
  }
  const float b2v = (lr < 3) ? b2[lr] : 0.f;

  const int pp = lane & 7;          // point slot this lane precomputes

  for (int tile = blockIdx.x; tile < NTILES; tile += GRID) {
    const int base = tile * 64;

    // ---- gather + bilinear lerp (packed fp16 math) ----
    float2 cp = ((const float2*)coords)[base + 8*wv + pp];
    float c0 = fminf(fmaxf(cp.x, -1.f), 0.999f);
    float c1 = fminf(fmaxf(cp.y, -1.f), 0.999f);
    float a0 = (0.5f*c0 + 0.5f) * 511.f;
    float a1 = (0.5f*c1 + 0.5f) * 511.f;
    int i0 = (int)a0, i1 = (int)a1;
    float wa = a0 - (float)i0, wb = a1 - (float)i1;
    int o0 = i0 << 9, o1 = i1 << 9;      // byte row offsets (512 B/row)

#pragma unroll
    for (int i = 0; i < 8; ++i) {
      int   oo0 = __shfl(o0, i);
      int   oo1 = __shfl(o1, i);
      float waf = __shfl(wa, i);
      float wbf = __shfl(wb, i);
      _Float16 wah = (_Float16)waf, wbh = (_Float16)wbf;
      f16x4 wa4 = {wah, wah, wah, wah};
      f16x4 wb4 = {wbh, wbh, wbh, wbh};
      const char* px = (const char*)emb0h + oo0 + 8*lane;   // lane covers elems 4l..4l+3
      const char* py = (const char*)emb1h + oo1 + 8*lane;
      f16x4 x0 = *(const f16x4*)px;
      f16x4 x1 = *(const f16x4*)(px + 512);
      f16x4 y0 = *(const f16x4*)py;
      f16x4 y1 = *(const f16x4*)(py + 512);
      f16x4 ev = (x0 + wa4*(x1 - x0)) * (y0 + wb4*(y1 - y0));
      int row = 8*wv + i;
      *(f16x4*)(eb + row*512 + ((8*lane) ^ ((row & 7) << 4))) = ev;
    }
    __syncthreads();

    // ---- layer 0: [64x256] @ [256x128], wave covers all 64 rows x its 16 cols ----
    f32x4 acc0[4];
#pragma unroll
    for (int mt = 0; mt < 4; ++mt) acc0[mt] = (f32x4)0.f;
#pragma unroll
    for (int ks = 0; ks < 8; ++ks)
#pragma unroll
      for (int mt = 0; mt < 4; ++mt) {
        int row = 16*mt + lr;
        f16x8 a = *(const f16x8*)(eb + row*512 + ((64*ks + 16*g) ^ ((lr & 7) << 4)));
        acc0[mt] = __builtin_amdgcn_mfma_f32_16x16x32_f16(a, w0f[ks], acc0[mt], 0, 0, 0);
      }
    // epilogue: sin(30(x+b)) -> h_smem   (C layout: row=16mt+4g+r, col=16wv+lr)
#pragma unroll
    for (int mt = 0; mt < 4; ++mt)
#pragma unroll
      for (int r = 0; r < 4; ++r) {
        float h = __sinf(30.f * (acc0[mt][r] + b0v));
        int row  = 16*mt + 4*g + r;
        int colb = 2*(16*wv + lr);
        *(_Float16*)(hb + row*256 + (colb ^ ((row & 7) << 4))) = (_Float16)h;
      }
    __syncthreads();

    // ---- layer 1: [64x128] @ [128x128], 16 cols/wave ----
    f32x4 acc1[4];
#pragma unroll
    for (int mt = 0; mt < 4; ++mt) acc1[mt] = (f32x4)0.f;
#pragma unroll
    for (int ks = 0; ks < 4; ++ks)
#pragma unroll
      for (int mt = 0; mt < 4; ++mt) {
        int row = 16*mt + lr;
        f16x8 a = *(const f16x8*)(hb + row*256 + ((64*ks + 16*g) ^ ((lr & 7) << 4)));
        acc1[mt] = __builtin_amdgcn_mfma_f32_16x16x32_f16(a, w1f[ks], acc1[mt], 0, 0, 0);
      }
    __syncthreads();   // all h0 reads done before h1 overwrites
#pragma unroll
    for (int mt = 0; mt < 4; ++mt)
#pragma unroll
      for (int r = 0; r < 4; ++r) {
        float h = __sinf(30.f * (acc1[mt][r] + b1v));
        int row  = 16*mt + 4*g + r;
        int colb = 2*(16*wv + lr);
        *(_Float16*)(hb + row*256 + (colb ^ ((row & 7) << 4))) = (_Float16)h;
      }
    __syncthreads();

    // ---- layer 2: [64x128] @ [128x3] (padded to 16 cols), waves 0-3 ----
    if (wv < 4) {
      f32x4 acc2 = (f32x4)0.f;
#pragma unroll
      for (int ks = 0; ks < 4; ++ks) {
        int row = 16*wv + lr;
        f16x8 a = *(const f16x8*)(hb + row*256 + ((64*ks + 16*g) ^ ((lr & 7) << 4)));
        acc2 = __builtin_amdgcn_mfma_f32_16x16x32_f16(a, w2f[ks], acc2, 0, 0, 0);
      }
      if (lr < 3) {
#pragma unroll
        for (int r = 0; r < 4; ++r) {
          int pt = base + 16*wv + 4*g + r;
          out[pt*3 + lr] = acc2[r] + b2v;
        }
      }
    }
    // e_smem writes of tile t+1 happen before t+1's first barrier; all e/h
    // reads of tile t precede barriers the writers already crossed -> safe.
  }
}

extern "C" void kernel_launch(void* const* d_in, const int* in_sizes, int n_in,
                              void* d_out, int out_size, void* d_ws, size_t ws_size,
                              hipStream_t stream) {
  const float* coords = (const float*)d_in[0];
  const float* emb0   = (const float*)d_in[1];
  const float* emb1   = (const float*)d_in[2];
  const float* w0     = (const float*)d_in[3];
  const float* b0     = (const float*)d_in[4];
  const float* w1     = (const float*)d_in[5];
  const float* b1     = (const float*)d_in[6];
  const float* w2     = (const float*)d_in[7];
  const float* b2     = (const float*)d_in[8];
  float* out = (float*)d_out;
  _Float16* ws = (_Float16*)d_ws;

  // fp16 conversion of tables + weights into workspace (idempotent, every call)
  prep_kernel<<<(155840 + 255)/256, 256, 0, stream>>>(emb0, emb1, w0, w1, w2, (f16x2*)ws);

  axisnet_kernel<<<GRID, 512, 0, stream>>>(coords, b0, b1, b2,
                                           (const _Float16*)ws, out);
}

// Round 5
// 323.246 us; speedup vs baseline: 2.0536x; 1.1206x over previous
//
#include <hip/hip_runtime.h>
#include <hip/hip_fp16.h>

typedef __attribute__((ext_vector_type(8))) _Float16 f16x8;
typedef __attribute__((ext_vector_type(2))) _Float16 f16x2;
typedef __attribute__((ext_vector_type(4))) float f32x4;
typedef __attribute__((ext_vector_type(16))) float f32x16;

#define ED 256
#define HID 128
#define NTILES 16384          // 1M points / 64 per tile
#define GRID 512

// d_ws layout (units: halfs)
#define WS_EMB0 0
#define WS_EMB1 131072
#define WS_W0   262144
#define WS_W1   294912
#define WS_W2   311296

__global__ void prep_kernel(const float* __restrict__ emb0, const float* __restrict__ emb1,
                            const float* __restrict__ w0, const float* __restrict__ w1,
                            const float* __restrict__ w2, f16x2* __restrict__ dst) {
  int idx = blockIdx.x * 256 + threadIdx.x;       // f32-pair index == f16-pair index
  const float* src; int rel;
  if      (idx <  65536) { src = emb0; rel = idx; }
  else if (idx < 131072) { src = emb1; rel = idx - 65536; }
  else if (idx < 147456) { src = w0;   rel = idx - 131072; }
  else if (idx < 155648) { src = w1;   rel = idx - 147456; }
  else if (idx < 155840) { src = w2;   rel = idx - 155648; }
  else return;
  float2 v = ((const float2*)src)[rel];
  f16x2 h; h[0] = (_Float16)v.x; h[1] = (_Float16)v.y;
  dst[idx] = h;
}

// (512,2): 2 blocks/CU min -> 128-VGPR cap (pool = 512/SIMD, 4 waves/SIMD).
__global__ __launch_bounds__(512, 2) void axisnet_kernel(
    const float* __restrict__ coords,
    const float* __restrict__ b0, const float* __restrict__ b1,
    const float* __restrict__ b2,
    const _Float16* __restrict__ ws, float* __restrict__ out)
{
  __shared__ _Float16 e_smem[64 * 256];   // 32 KiB, 512 B rows, XOR-swizzled
  __shared__ _Float16 h_smem[64 * 128];   // 16 KiB, 256 B rows, XOR-swizzled
  char* eb = (char*)e_smem;
  char* hb = (char*)h_smem;

  const _Float16* emb0h = ws + WS_EMB0;
  const _Float16* emb1h = ws + WS_EMB1;
  const _Float16* w0h   = ws + WS_W0;
  const _Float16* w1h   = ws + WS_W1;
  const _Float16* w2h   = ws + WS_W2;

  const int tid  = threadIdx.x;
  const int lane = tid & 63;
  const int wv   = tid >> 6;        // 0..7
  const int hi   = lane >> 5;       // 0/1  (32x32 k-half)
  const int l5   = lane & 31;
  const int g    = lane >> 4;       // 0..3 (16x16 k-group)
  const int lr   = lane & 15;
  const int wm   = wv >> 2;         // L0 row-block (32 rows)
  const int wc   = wv & 3;          // L0 col-block (32 cols)

  // ---- persistent B fragments ----
  // L0 (32x32x16): col = 32*wc + l5, k = 16*ks + 8*hi + j  -> 16 x f16x8 = 64 VGPR
  f16x8 w0f[16];
  {
    const _Float16* p = w0h + (size_t)(32*wc + l5)*ED + 8*hi;
#pragma unroll
    for (int ks = 0; ks < 16; ++ks) w0f[ks] = *(const f16x8*)(p + 16*ks);
  }
  const float b0v = b0[32*wc + l5];

  // L1 (16x16x32): col = 16*wv + lr, k = 32*ks + 8*g + j  -> 16 VGPR
  f16x8 w1f[4];
  {
    const _Float16* p = w1h + (size_t)(16*wv + lr)*HID + 8*g;
#pragma unroll
    for (int ks = 0; ks < 4; ++ks) w1f[ks] = *(const f16x8*)(p + 32*ks);
  }
  const float b1v = b1[16*wv + lr];
  const float b2v = (lr < 3) ? b2[lr] : 0.f;

  // ---- gather: 4 iters, lane covers 16 B of one row (32 lanes/row, 2 rows/iter)
#define GATHER(T) do {                                                        \
    int base2 = (T)*64 + 8*wv;                                                \
    _Pragma("unroll")                                                         \
    for (int it = 0; it < 4; ++it) {                                          \
      int pt = base2 + 2*it + hi;                                             \
      float2 cp = ((const float2*)coords)[pt];                                \
      float c0 = fminf(fmaxf(cp.x, -1.f), 0.999f);                            \
      float c1 = fminf(fmaxf(cp.y, -1.f), 0.999f);                            \
      float a0 = (0.5f*c0 + 0.5f) * 511.f;                                    \
      float a1 = (0.5f*c1 + 0.5f) * 511.f;                                    \
      int i0 = (int)a0, i1 = (int)a1;                                         \
      _Float16 wa = (_Float16)(a0 - (float)i0);                               \
      _Float16 wb = (_Float16)(a1 - (float)i1);                               \
      f16x8 wa8 = {wa,wa,wa,wa,wa,wa,wa,wa};                                  \
      f16x8 wb8 = {wb,wb,wb,wb,wb,wb,wb,wb};                                  \
      const char* px = (const char*)emb0h + (i0 << 9) + 16*l5;                \
      const char* py = (const char*)emb1h + (i1 << 9) + 16*l5;                \
      f16x8 x0 = *(const f16x8*)px, x1 = *(const f16x8*)(px + 512);           \
      f16x8 y0 = *(const f16x8*)py, y1 = *(const f16x8*)(py + 512);           \
      f16x8 ev = (x0 + wa8*(x1 - x0)) * (y0 + wb8*(y1 - y0));                 \
      int row = 8*wv + 2*it + hi;                                             \
      *(f16x8*)(eb + row*512 + ((16*l5) ^ ((row & 7) << 4))) = ev;            \
    } } while (0)

  GATHER(blockIdx.x);               // prologue: e(tile0)

  for (int tile = blockIdx.x; tile < NTILES; tile += GRID) {
    const int base = tile * 64;
    __syncthreads();                               // bar1: e ready; prev L2 h-reads done

    // ---- L0: [64x256]@[256x128], wave = 32 rows x 32 cols, 32x32x16 MFMA ----
    {
      f32x16 acc0 = (f32x16)0.f;
      const int arow = 32*wm + l5;
      const char* abase = eb + arow*512;
      const int aswz = (arow & 7) << 4;
#pragma unroll
      for (int ks = 0; ks < 16; ++ks) {
        f16x8 a = *(const f16x8*)(abase + ((32*ks + 16*hi) ^ aswz));
        acc0 = __builtin_amdgcn_mfma_f32_32x32x16_f16(a, w0f[ks], acc0, 0, 0, 0);
      }
      // epilogue: C: col = 32*wc + l5, row = 32*wm + (reg&3)+8*(reg>>2)+4*hi
      const int colb = 2*(32*wc + l5);
#pragma unroll
      for (int reg = 0; reg < 16; ++reg) {
        float h = __sinf(30.f * (acc0[reg] + b0v));
        int hrow = 32*wm + (reg & 3) + 8*(reg >> 2) + 4*hi;
        *(_Float16*)(hb + hrow*256 + (colb ^ ((hrow & 7) << 4))) = (_Float16)h;
      }
    }
    __syncthreads();                               // bar2: h0 ready; e reads done

    // ---- gather(t+GRID) overlapped with L1 (same barrier region) ----
    if (tile + GRID < NTILES) GATHER(tile + GRID);

    // ---- L1: [64x128]@[128x128], 16 cols/wave, 16x16x32 MFMA ----
    f32x4 acc1[4];
#pragma unroll
    for (int mt = 0; mt < 4; ++mt) acc1[mt] = (f32x4)0.f;
#pragma unroll
    for (int ks = 0; ks < 4; ++ks)
#pragma unroll
      for (int mt = 0; mt < 4; ++mt) {
        int row = 16*mt + lr;
        f16x8 a = *(const f16x8*)(hb + row*256 + ((64*ks + 16*g) ^ ((lr & 7) << 4)));
        acc1[mt] = __builtin_amdgcn_mfma_f32_16x16x32_f16(a, w1f[ks], acc1[mt], 0, 0, 0);
      }
    __syncthreads();                               // bar3: all h0 reads done
#pragma unroll
    for (int mt = 0; mt < 4; ++mt)
#pragma unroll
      for (int r = 0; r < 4; ++r) {
        float h = __sinf(30.f * (acc1[mt][r] + b1v));
        int row  = 16*mt + 4*g + r;
        int colb = 2*(16*wv + lr);
        *(_Float16*)(hb + row*256 + (colb ^ ((row & 7) << 4))) = (_Float16)h;
      }
    __syncthreads();                               // bar4: h1 ready

    // ---- L2: [64x128]@[128x3] (padded to 16 cols), waves 0-3, 16x16x32 ----
    if (wv < 4) {
      f32x4 acc2 = (f32x4)0.f;
#pragma unroll
      for (int ks = 0; ks < 4; ++ks) {
        f16x8 bfrag = (f16x8)0;
        if (lr < 3) bfrag = *(const f16x8*)(w2h + (size_t)lr*HID + 32*ks + 8*g);
        int row = 16*wv + lr;
        f16x8 a = *(const f16x8*)(hb + row*256 + ((64*ks + 16*g) ^ ((lr & 7) << 4)));
        acc2 = __builtin_amdgcn_mfma_f32_16x16x32_f16(a, bfrag, acc2, 0, 0, 0);
      }
      if (lr < 3) {
#pragma unroll
        for (int r = 0; r < 4; ++r) {
          int pt = base + 16*wv + 4*g + r;
          out[pt*3 + lr] = acc2[r] + b2v;
        }
      }
    }
  }
}

extern "C" void kernel_launch(void* const* d_in, const int* in_sizes, int n_in,
                              void* d_out, int out_size, void* d_ws, size_t ws_size,
                              hipStream_t stream) {
  const float* coords = (const float*)d_in[0];
  const float* emb0   = (const float*)d_in[1];
  const float* emb1   = (const float*)d_in[2];
  const float* w0     = (const float*)d_in[3];
  const float* b0     = (const float*)d_in[4];
  const float* w1     = (const float*)d_in[5];
  const float* b1     = (const float*)d_in[6];
  const float* w2     = (const float*)d_in[7];
  const float* b2     = (const float*)d_in[8];
  float* out = (float*)d_out;
  _Float16* ws = (_Float16*)d_ws;

  prep_kernel<<<(155840 + 255)/256, 256, 0, stream>>>(emb0, emb1, w0, w1, w2, (f16x2*)ws);
  axisnet_kernel<<<GRID, 512, 0, stream>>>(coords, b0, b1, b2,
                                           (const _Float16*)ws, out);
}

// Round 6
// 303.012 us; speedup vs baseline: 2.1907x; 1.0668x over previous
//
#include <hip/hip_runtime.h>
#include <hip/hip_fp16.h>

typedef __attribute__((ext_vector_type(8))) _Float16 f16x8;
typedef __attribute__((ext_vector_type(2))) _Float16 f16x2;
typedef __attribute__((ext_vector_type(4))) float f32x4;
typedef __attribute__((ext_vector_type(16))) float f32x16;

#define ED 256
#define HID 128
#define NTILES 16384          // 1M points / 64 per tile
#define GRID 512
#define K_REV 4.7746482927568605f   // 30 / (2*pi): sin(30x) = sin_rev(x*K_REV)

// d_ws layout (units: halfs)
#define WS_EMB0 0
#define WS_EMB1 131072
#define WS_W0   262144
#define WS_W1   294912
#define WS_W2   311296

__global__ void prep_kernel(const float* __restrict__ emb0, const float* __restrict__ emb1,
                            const float* __restrict__ w0, const float* __restrict__ w1,
                            const float* __restrict__ w2, f16x2* __restrict__ dst) {
  int idx = blockIdx.x * 256 + threadIdx.x;       // f32-pair index == f16-pair index
  const float* src; int rel;
  if      (idx <  65536) { src = emb0; rel = idx; }
  else if (idx < 131072) { src = emb1; rel = idx - 65536; }
  else if (idx < 147456) { src = w0;   rel = idx - 131072; }
  else if (idx < 155648) { src = w1;   rel = idx - 147456; }
  else if (idx < 155840) { src = w2;   rel = idx - 155648; }
  else return;
  float2 v = ((const float2*)src)[rel];
  f16x2 h; h[0] = (_Float16)v.x; h[1] = (_Float16)v.y;
  dst[idx] = h;
}

// sin(2*pi*t) via hw v_fract + v_sin (3 VALU ops incl. the caller's fma)
__device__ __forceinline__ float fast_sin_rev(float t) {
#if __has_builtin(__builtin_amdgcn_fractf) && __has_builtin(__builtin_amdgcn_sinf)
  return __builtin_amdgcn_sinf(__builtin_amdgcn_fractf(t));
#else
  return __sinf(6.28318530718f * (t - floorf(t)));
#endif
}

// (512,2): 2 blocks/CU min -> 128-VGPR cap (pool = 512/SIMD, 4 waves/SIMD).
__global__ __launch_bounds__(512, 2) void axisnet_kernel(
    const float* __restrict__ coords,
    const float* __restrict__ b0, const float* __restrict__ b1,
    const float* __restrict__ b2,
    const _Float16* __restrict__ ws, float* __restrict__ out)
{
  __shared__ _Float16 e_smem[64 * 256];    // 32 KiB, 512 B rows, XOR-swizzled
  __shared__ _Float16 h0_smem[64 * 128];   // 16 KiB, 256 B rows, XOR-swizzled
  __shared__ _Float16 h1_smem[64 * 128];   // 16 KiB (separate buf -> fewer barriers)
  char* eb  = (char*)e_smem;
  char* h0b = (char*)h0_smem;
  char* h1b = (char*)h1_smem;

  const _Float16* emb0h = ws + WS_EMB0;
  const _Float16* emb1h = ws + WS_EMB1;
  const _Float16* w0h   = ws + WS_W0;
  const _Float16* w1h   = ws + WS_W1;
  const _Float16* w2h   = ws + WS_W2;

  const int tid  = threadIdx.x;
  const int lane = tid & 63;
  const int wv   = tid >> 6;        // 0..7
  const int hi   = lane >> 5;       // 0/1  (32x32 k-half)
  const int l5   = lane & 31;
  const int g    = lane >> 4;       // 0..3 (16x16 k-group)
  const int lr   = lane & 15;
  const int wm   = wv >> 2;         // L0 row-block (32 rows)
  const int wc   = wv & 3;          // L0 col-block (32 cols)

  // ---- persistent B fragments ----
  // L0 (32x32x16): col = 32*wc + l5, k = 16*ks + 8*hi + j  -> 64 VGPR
  f16x8 w0f[16];
  {
    const _Float16* p = w0h + (size_t)(32*wc + l5)*ED + 8*hi;
#pragma unroll
    for (int ks = 0; ks < 16; ++ks) w0f[ks] = *(const f16x8*)(p + 16*ks);
  }
  const float b0k = b0[32*wc + l5] * K_REV;

  // L1 (16x16x32): col = 16*wv + lr, k = 32*ks + 8*g + j  -> 16 VGPR
  f16x8 w1f[4];
  {
    const _Float16* p = w1h + (size_t)(16*wv + lr)*HID + 8*g;
#pragma unroll
    for (int ks = 0; ks < 4; ++ks) w1f[ks] = *(const f16x8*)(p + 32*ks);
  }
  const float b1k = b1[16*wv + lr] * K_REV;
  const float b2v = (lr < 3) ? b2[lr] : 0.f;

  // ---- gather: setup computed once per lane (point = lane&7), shfl-broadcast ----
#define GATHER(T) do {                                                        \
    const int base2 = (T)*64 + 8*wv;                                          \
    float2 cp = ((const float2*)coords)[base2 + (lane & 7)];                  \
    float c0 = fminf(fmaxf(cp.x, -1.f), 0.999f);                              \
    float c1 = fminf(fmaxf(cp.y, -1.f), 0.999f);                              \
    float a0 = (0.5f*c0 + 0.5f) * 511.f;                                      \
    float a1 = (0.5f*c1 + 0.5f) * 511.f;                                      \
    int i0 = (int)a0, i1 = (int)a1;                                           \
    int o0 = i0 << 9, o1 = i1 << 9;      /* byte row offsets (512 B/row) */   \
    unsigned short ua = __builtin_bit_cast(unsigned short, (_Float16)(a0 - (float)i0)); \
    unsigned short ub = __builtin_bit_cast(unsigned short, (_Float16)(a1 - (float)i1)); \
    int wp = (int)ua | ((int)ub << 16);                                       \
    _Pragma("unroll")                                                         \
    for (int it = 0; it < 4; ++it) {                                          \
      int src = 2*it + hi;                                                    \
      int oo0 = __shfl(o0, src);                                              \
      int oo1 = __shfl(o1, src);                                              \
      int wpp = __shfl(wp, src);                                              \
      _Float16 wah = __builtin_bit_cast(_Float16, (unsigned short)(wpp & 0xffff));      \
      _Float16 wbh = __builtin_bit_cast(_Float16, (unsigned short)((unsigned)wpp >> 16)); \
      f16x8 wa8 = {wah,wah,wah,wah,wah,wah,wah,wah};                          \
      f16x8 wb8 = {wbh,wbh,wbh,wbh,wbh,wbh,wbh,wbh};                          \
      const char* px = (const char*)emb0h + oo0 + 16*l5;                      \
      const char* py = (const char*)emb1h + oo1 + 16*l5;                      \
      f16x8 x0 = *(const f16x8*)px, x1 = *(const f16x8*)(px + 512);           \
      f16x8 y0 = *(const f16x8*)py, y1 = *(const f16x8*)(py + 512);           \
      f16x8 ev = (x0 + wa8*(x1 - x0)) * (y0 + wb8*(y1 - y0));                 \
      int row = 8*wv + 2*it + hi;                                             \
      *(f16x8*)(eb + row*512 + ((16*l5) ^ ((row & 7) << 4))) = ev;            \
    } } while (0)

  GATHER(blockIdx.x);               // prologue: e(tile0)
  __syncthreads();                  // e ready

  // Per-tile barrier schedule (2 barriers):
  //   [top] L2(prev) reads h1 (waves 0-3)  ||  L0(t) reads e, writes h0
  //   bar_B: h0 ready (and everyone's L2/h1-reads + e-reads done)
  //   GATHER(t+1) writes e  ||  L1 reads h0, writes h1
  //   bar_C: h1 + e(t+1) ready
  int prev_base = -1;
  for (int tile = blockIdx.x; tile < NTILES; tile += GRID) {
    const int base = tile * 64;

    // ---- L2(prev): [64x128]@[128x3], waves 0-3, reads h1; overlaps L0 below ----
    if (prev_base >= 0 && wv < 4) {
      f32x4 acc2 = (f32x4)0.f;
#pragma unroll
      for (int ks = 0; ks < 4; ++ks) {
        f16x8 bfrag = (f16x8)0;
        if (lr < 3) bfrag = *(const f16x8*)(w2h + (size_t)lr*HID + 32*ks + 8*g);
        int row = 16*wv + lr;
        f16x8 a = *(const f16x8*)(h1b + row*256 + ((64*ks + 16*g) ^ ((row & 7) << 4)));
        acc2 = __builtin_amdgcn_mfma_f32_16x16x32_f16(a, bfrag, acc2, 0, 0, 0);
      }
      if (lr < 3) {
#pragma unroll
        for (int r = 0; r < 4; ++r) {
          int pt = prev_base + 16*wv + 4*g + r;
          out[pt*3 + lr] = acc2[r] + b2v;
        }
      }
    }

    // ---- L0: [64x256]@[256x128], wave = 32 rows x 32 cols, 32x32x16 MFMA ----
    {
      f32x16 acc0 = (f32x16)0.f;
      const int arow = 32*wm + l5;
      const char* abase = eb + arow*512;
      const int aswz = (arow & 7) << 4;
#pragma unroll
      for (int ks = 0; ks < 16; ++ks) {
        f16x8 a = *(const f16x8*)(abase + ((32*ks + 16*hi) ^ aswz));
        acc0 = __builtin_amdgcn_mfma_f32_32x32x16_f16(a, w0f[ks], acc0, 0, 0, 0);
      }
      // C: col = 32*wc + l5, row = 32*wm + (reg&3)+8*(reg>>2)+4*hi
      const int colb = 2*(32*wc + l5);
#pragma unroll
      for (int reg = 0; reg < 16; ++reg) {
        float s = fast_sin_rev(fmaf(acc0[reg], K_REV, b0k));
        int hrow = 32*wm + (reg & 3) + 8*(reg >> 2) + 4*hi;
        *(_Float16*)(h0b + hrow*256 + (colb ^ ((hrow & 7) << 4))) = (_Float16)s;
      }
    }
    __syncthreads();                               // bar_B: h0 ready

    // ---- gather(t+GRID) (writes e) overlapped with L1 ----
    if (tile + GRID < NTILES) GATHER(tile + GRID);

    // ---- L1: [64x128]@[128x128], 16 cols/wave, 16x16x32 MFMA, h0 -> h1 ----
    f32x4 acc1[4];
#pragma unroll
    for (int mt = 0; mt < 4; ++mt) acc1[mt] = (f32x4)0.f;
#pragma unroll
    for (int ks = 0; ks < 4; ++ks)
#pragma unroll
      for (int mt = 0; mt < 4; ++mt) {
        int row = 16*mt + lr;
        f16x8 a = *(const f16x8*)(h0b + row*256 + ((64*ks + 16*g) ^ ((lr & 7) << 4)));
        acc1[mt] = __builtin_amdgcn_mfma_f32_16x16x32_f16(a, w1f[ks], acc1[mt], 0, 0, 0);
      }
#pragma unroll
    for (int mt = 0; mt < 4; ++mt)
#pragma unroll
      for (int r = 0; r < 4; ++r) {
        float s = fast_sin_rev(fmaf(acc1[mt][r], K_REV, b1k));
        int row  = 16*mt + 4*g + r;
        int colb = 2*(16*wv + lr);
        *(_Float16*)(h1b + row*256 + (colb ^ ((row & 7) << 4))) = (_Float16)s;
      }
    __syncthreads();                               // bar_C: h1 + e(t+1) ready
    prev_base = base;
  }

  // ---- epilogue: L2 of the last tile ----
  if (prev_base >= 0 && wv < 4) {
    f32x4 acc2 = (f32x4)0.f;
#pragma unroll
    for (int ks = 0; ks < 4; ++ks) {
      f16x8 bfrag = (f16x8)0;
      if (lr < 3) bfrag = *(const f16x8*)(w2h + (size_t)lr*HID + 32*ks + 8*g);
      int row = 16*wv + lr;
      f16x8 a = *(const f16x8*)(h1b + row*256 + ((64*ks + 16*g) ^ ((row & 7) << 4)));
      acc2 = __builtin_amdgcn_mfma_f32_16x16x32_f16(a, bfrag, acc2, 0, 0, 0);
    }
    if (lr < 3) {
#pragma unroll
      for (int r = 0; r < 4; ++r) {
        int pt = prev_base + 16*wv + 4*g + r;
        out[pt*3 + lr] = acc2[r] + b2v;
      }
    }
  }
}

extern "C" void kernel_launch(void* const* d_in, const int* in_sizes, int n_in,
                              void* d_out, int out_size, void* d_ws, size_t ws_size,
                              hipStream_t stream) {
  const float* coords = (const float*)d_in[0];
  const float* emb0   = (const float*)d_in[1];
  const float* emb1   = (const float*)d_in[2];
  const float* w0     = (const float*)d_in[3];
  const float* b0     = (const float*)d_in[4];
  const float* w1     = (const float*)d_in[5];
  const float* b1     = (const float*)d_in[6];
  const float* w2     = (const float*)d_in[7];
  const float* b2     = (const float*)d_in[8];
  float* out = (float*)d_out;
  _Float16* ws = (_Float16*)d_ws;

  prep_kernel<<<(155840 + 255)/256, 256, 0, stream>>>(emb0, emb1, w0, w1, w2, (f16x2*)ws);
  axisnet_kernel<<<GRID, 512, 0, stream>>>(coords, b0, b1, b2,
                                           (const _Float16*)ws, out);
}